// Round 11
// baseline (417.522 us; speedup 1.0000x reference)
//
#include <hip/hip_runtime.h>
#include <hip/hip_bf16.h>
#include <math.h>

// GCN bf16 pipeline (round 10):
//   CSR build (histogram/scan/scatter)
//   feat -> bf16 BLOCKED [fb][node][32] ; W1,W2 -> bf16 [N][K] ; W3 -> bf16 padded [64][256]
//   agg1 = seg_sum(featb_blk) -> row-major ; h1 = relu(agg1@W1+b1) -> BLOCKED  (MFMA)
//   agg2 = seg_sum(h1_blk)    -> row-major ; h2 = relu(agg2@W2+b2) -> row-major (MFMA)
//   P = h2 @ W3                                                     (MFMA, B in regs)
//   out = log_softmax(seg_sum(P) + b3) ; out[N*40] = 3N
// Aggregation: feature-sliced for XCD-L2 locality (fb = blockIdx&7, slice = 3.2MB
// blocked region) BUT with full-width instructions: wave = 16 groups x 4 lanes,
// group = dst node, lane = 16B of the 64B slice -> 1KB per wave load instruction.

typedef __attribute__((ext_vector_type(8))) short bf16x8;
typedef __attribute__((ext_vector_type(4))) float f32x4;

static __device__ __forceinline__ short f2b(float f) {
    union { float f; unsigned u; } v; v.f = f;
    unsigned r = (v.u + 0x7FFFu + ((v.u >> 16) & 1u)) >> 16;
    return (short)r;
}
static __device__ __forceinline__ float b2f(short h) {
    union { unsigned u; float f; } v; v.u = ((unsigned)(unsigned short)h) << 16;
    return v.f;
}
static __device__ __forceinline__ bf16x8 bzero8() {
    bf16x8 v;
#pragma unroll
    for (int j = 0; j < 8; ++j) v[j] = 0;
    return v;
}

// ---------------- CSR build ----------------

__global__ __launch_bounds__(256) void k_count(const int* __restrict__ dst,
                                               int* __restrict__ cnt, int E) {
    int e = blockIdx.x * 256 + threadIdx.x;
    if (e < E) atomicAdd(&cnt[dst[e]], 1);
}

__global__ __launch_bounds__(256) void k_scan1(const int* __restrict__ cnt,
                                               int* __restrict__ inc,
                                               int* __restrict__ bsum, int n) {
    __shared__ int sh[256];
    int t = threadIdx.x;
    int i = blockIdx.x * 256 + t;
    int v = (i < n) ? cnt[i] : 0;
    sh[t] = v;
    __syncthreads();
    for (int s = 1; s < 256; s <<= 1) {
        int x = (t >= s) ? sh[t - s] : 0;
        __syncthreads();
        sh[t] += x;
        __syncthreads();
    }
    if (i < n) inc[i] = sh[t];
    if (t == 255) bsum[blockIdx.x] = sh[255];
}

__global__ __launch_bounds__(256) void k_scan2(const int* __restrict__ bsum,
                                               int* __restrict__ ebo, int nb) {
    __shared__ int sh[256];
    int t = threadIdx.x;
    int v = (t < nb) ? bsum[t] : 0;
    sh[t] = v;
    __syncthreads();
    for (int s = 1; s < 256; s <<= 1) {
        int x = (t >= s) ? sh[t - s] : 0;
        __syncthreads();
        sh[t] += x;
        __syncthreads();
    }
    ebo[t] = sh[t] - v;
}

__global__ __launch_bounds__(256) void k_scan3(const int* __restrict__ inc,
                                               const int* __restrict__ cnt,
                                               const int* __restrict__ ebo,
                                               int* __restrict__ off,
                                               int* __restrict__ pos, int n) {
    int i = blockIdx.x * 256 + threadIdx.x;
    if (i < n) {
        int ib = inc[i] + ebo[blockIdx.x];
        int ex = ib - cnt[i];
        off[i] = ex;
        pos[i] = ex;
        if (i == n - 1) off[n] = ib;
    }
}

__global__ __launch_bounds__(256) void k_scatter(const int* __restrict__ src,
                                                 const int* __restrict__ dst,
                                                 int* __restrict__ pos,
                                                 int* __restrict__ esrc, int E) {
    int e = blockIdx.x * 256 + threadIdx.x;
    if (e < E) {
        int p = atomicAdd(&pos[dst[e]], 1);
        esrc[p] = src[e];
    }
}

// ---------------- converts ----------------

// feat (f32 row-major [n][256]) -> blocked bf16 [fb][node][32]
__global__ __launch_bounds__(256) void k_cvt_blk(const float* __restrict__ X,
                                                 short* __restrict__ Yblk, int n) {
    int i = blockIdx.x * 256 + threadIdx.x;  // one thread = 4 consecutive feats
    int stride = gridDim.x * 256;
    int total = n * 64;
    for (; i < total; i += stride) {
        int node = i >> 6;
        int rem = i & 63;
        int fb = rem >> 3;
        int c4 = rem & 7;
        float4 v = ((const float4*)X)[i];
        short4 o;
        o.x = f2b(v.x); o.y = f2b(v.y); o.z = f2b(v.z); o.w = f2b(v.w);
        *(short4*)&Yblk[((size_t)fb * n + node) * 32 + c4 * 4] = o;
    }
}

// fused weight converts: Wt1[n][k], Wt2[n][k] (256x256), Wt3p[c][k] (64x256, zero-padded)
__global__ __launch_bounds__(256) void k_cvt_weights(const float* __restrict__ W1,
                                                     const float* __restrict__ W2,
                                                     const float* __restrict__ W3,
                                                     short* __restrict__ Wt1,
                                                     short* __restrict__ Wt2,
                                                     short* __restrict__ Wt3p) {
    int b = blockIdx.x, t = threadIdx.x;
    if (b < 256) {
        int idx = b * 256 + t;
        int nn = idx >> 8, k = idx & 255;
        Wt1[idx] = f2b(W1[k * 256 + nn]);
    } else if (b < 512) {
        int idx = (b - 256) * 256 + t;
        int nn = idx >> 8, k = idx & 255;
        Wt2[idx] = f2b(W2[k * 256 + nn]);
    } else {
        int idx = (b - 512) * 256 + t;
        int c = idx >> 8, k = idx & 255;
        Wt3p[idx] = (c < 40) ? f2b(W3[k * 40 + c]) : (short)0;
    }
}

// ---------------- feature-sliced aggregation, full-width ----------------
// input blocked [fb][node][32]; output row-major [node][256].
// block -> fb = blockIdx&7 (XCD-aligned). 64 groups of 4 lanes per block;
// group = one dst node; lane j loads 16B of the node's 64B slice per edge.
// One wave load instr = 16 groups x 64B = 1KB, all from the 3.2MB slice.

__global__ __launch_bounds__(256) void k_agg_s(const short* __restrict__ Xblk,
                                               const int* __restrict__ off,
                                               const int* __restrict__ esrc,
                                               short* __restrict__ Y, int n) {
    const int fb = blockIdx.x & 7;
    const int chunk = blockIdx.x >> 3;
    const int t = threadIdx.x;
    const int g = t >> 2;      // 0..63: node within chunk
    const int j = t & 3;       // 16B sub-slice
    const short* Xs = Xblk + (size_t)fb * n * 32;
    int dst = chunk * 64 + g;
    if (dst >= n) return;
    int s = off[dst], e = off[dst + 1];
    float acc[8];
#pragma unroll
    for (int k = 0; k < 8; ++k) acc[k] = 0.f;
    int i = s;
    for (; i + 1 < e; i += 2) {
        int u0 = esrc[i], u1 = esrc[i + 1];
        bf16x8 v0 = *(const bf16x8*)&Xs[(size_t)u0 * 32 + j * 8];
        bf16x8 v1 = *(const bf16x8*)&Xs[(size_t)u1 * 32 + j * 8];
#pragma unroll
        for (int k = 0; k < 8; ++k) acc[k] += b2f(v0[k]) + b2f(v1[k]);
    }
    if (i < e) {
        int u0 = esrc[i];
        bf16x8 v0 = *(const bf16x8*)&Xs[(size_t)u0 * 32 + j * 8];
#pragma unroll
        for (int k = 0; k < 8; ++k) acc[k] += b2f(v0[k]);
    }
    bf16x8 o;
#pragma unroll
    for (int k = 0; k < 8; ++k) o[k] = f2b(acc[k]);
    *(bf16x8*)&Y[(size_t)dst * 256 + fb * 32 + j * 8] = o;
}

// ---------------- MFMA GEMM: (M x 256) bf16 @ Wt[256][256] bf16 + bias, relu -> bf16 ----------------
// BLKOUT=1: write blocked [fb][node][32]; else row-major.

template <int RELU, int BLKOUT>
__global__ __launch_bounds__(256) void k_gemm_mfma(const short* __restrict__ A,
                                                   const short* __restrict__ Wt,
                                                   const float* __restrict__ bias,
                                                   short* __restrict__ Y, int M) {
    __shared__ short smem[16384];  // 32 KB
    short* sA = smem;              // 2048 elems
    short* sB = smem + 2048;       // 8192 elems
    const int t = threadIdx.x;
    const int w = t >> 6, l = t & 63;
    const int lg = l >> 4, lr = l & 15;
    const int bm = blockIdx.x * 64;

    f32x4 acc[4][4];
#pragma unroll
    for (int a = 0; a < 4; ++a)
#pragma unroll
        for (int b = 0; b < 4; ++b) {
            acc[a][b][0] = 0.f; acc[a][b][1] = 0.f;
            acc[a][b][2] = 0.f; acc[a][b][3] = 0.f;
        }

    const int arow = bm + (t & 63);
    const int ag = t >> 6;
    const bool aok = (arow < M);

    bf16x8 ra, rb0, rb1, rb2, rb3;
    auto loadRegs = [&](int k0) {
        ra = aok ? *(const bf16x8*)&A[(size_t)arow * 256 + k0 + ag * 8] : bzero8();
        const short* wp = &Wt[(size_t)t * 256 + k0];
        rb0 = *(const bf16x8*)&wp[0];
        rb1 = *(const bf16x8*)&wp[8];
        rb2 = *(const bf16x8*)&wp[16];
        rb3 = *(const bf16x8*)&wp[24];
    };

    loadRegs(0);
    for (int kt = 0; kt < 8; ++kt) {
        __syncthreads();
        *(bf16x8*)&sA[t * 8] = ra;
        *(bf16x8*)&sB[t * 8] = rb0;
        *(bf16x8*)&sB[2048 + t * 8] = rb1;
        *(bf16x8*)&sB[4096 + t * 8] = rb2;
        *(bf16x8*)&sB[6144 + t * 8] = rb3;
        if (kt < 7) loadRegs((kt + 1) * 32);
        __syncthreads();

        bf16x8 af[4], bf[4];
#pragma unroll
        for (int rb = 0; rb < 4; ++rb)
            af[rb] = *(const bf16x8*)&sA[lg * 512 + (rb * 16 + lr) * 8];
#pragma unroll
        for (int cb = 0; cb < 4; ++cb)
            bf[cb] = *(const bf16x8*)&sB[lg * 2048 + ((w * 4 + cb) * 16 + lr) * 8];
#pragma unroll
        for (int rb = 0; rb < 4; ++rb)
#pragma unroll
            for (int cb = 0; cb < 4; ++cb)
                acc[rb][cb] = __builtin_amdgcn_mfma_f32_16x16x32_bf16(
                    af[rb], bf[cb], acc[rb][cb], 0, 0, 0);
    }

    __syncthreads();
    short* myreg = smem + w * 4096;  // wave-private [64][64]
#pragma unroll
    for (int cb = 0; cb < 4; ++cb) {
        float bb = bias[w * 64 + cb * 16 + lr];
#pragma unroll
        for (int rb = 0; rb < 4; ++rb)
#pragma unroll
            for (int r = 0; r < 4; ++r) {
                float x = acc[rb][cb][r] + bb;
                if (RELU) x = fmaxf(x, 0.f);
                myreg[(rb * 16 + lg * 4 + r) * 64 + cb * 16 + lr] = f2b(x);
            }
    }
#pragma unroll
    for (int j = 0; j < 8; ++j) {
        int row = j * 8 + (l >> 3);
        int grow = bm + row;
        bf16x8 v = *(const bf16x8*)&myreg[(j * 64 + l) * 8];
        if (grow < M) {
            if (BLKOUT) {
                int col = w * 64 + (l & 7) * 8;
                int fb = col >> 5, c32 = col & 31;
                *(bf16x8*)&Y[((size_t)fb * M + grow) * 32 + c32] = v;
            } else {
                *(bf16x8*)&Y[(size_t)grow * 256 + w * 64 + (l & 7) * 8] = v;
            }
        }
    }
}

// ---------------- P GEMM: (M x 256) bf16 @ Wt3p[64][256] bf16 -> P (M x 64) bf16 ----------------

__global__ __launch_bounds__(256) void k_gemmP(const short* __restrict__ A,
                                               const short* __restrict__ Wt3p,
                                               short* __restrict__ P, int M) {
    __shared__ short sA[2048];  // 4 KB
    const int t = threadIdx.x;
    const int w = t >> 6, l = t & 63;
    const int lg = l >> 4, lr = l & 15;
    const int bm = blockIdx.x * 64;

    bf16x8 bfr[8];
#pragma unroll
    for (int kt = 0; kt < 8; ++kt)
        bfr[kt] = *(const bf16x8*)&Wt3p[(size_t)(w * 16 + lr) * 256 + kt * 32 + lg * 8];

    f32x4 acc[4];
#pragma unroll
    for (int a = 0; a < 4; ++a) {
        acc[a][0] = 0.f; acc[a][1] = 0.f; acc[a][2] = 0.f; acc[a][3] = 0.f;
    }

    const int arow = bm + l;
    const bool aok = (arow < M);
    bf16x8 ra = aok ? *(const bf16x8*)&A[(size_t)arow * 256 + w * 8] : bzero8();

#pragma unroll
    for (int kt = 0; kt < 8; ++kt) {
        __syncthreads();
        *(bf16x8*)&sA[t * 8] = ra;
        if (kt < 7)
            ra = aok ? *(const bf16x8*)&A[(size_t)arow * 256 + (kt + 1) * 32 + w * 8]
                     : bzero8();
        __syncthreads();
        bf16x8 af[4];
#pragma unroll
        for (int rb = 0; rb < 4; ++rb)
            af[rb] = *(const bf16x8*)&sA[lg * 512 + (rb * 16 + lr) * 8];
#pragma unroll
        for (int rb = 0; rb < 4; ++rb)
            acc[rb] = __builtin_amdgcn_mfma_f32_16x16x32_bf16(af[rb], bfr[kt], acc[rb], 0, 0, 0);
    }

#pragma unroll
    for (int rb = 0; rb < 4; ++rb)
#pragma unroll
        for (int r = 0; r < 4; ++r) {
            int grow = bm + rb * 16 + lg * 4 + r;
            if (grow < M)
                P[(size_t)grow * 64 + w * 16 + lr] = f2b(acc[rb][r]);
        }
}

// ---------------- fused agg3 + bias + log_softmax: one wave per node ----------------

__global__ __launch_bounds__(256) void k_aggout(const short* __restrict__ P,
                                                const int* __restrict__ off,
                                                const int* __restrict__ esrc,
                                                const float* __restrict__ b3,
                                                float* __restrict__ out, int n,
                                                float node_count) {
    if (blockIdx.x == 0 && threadIdx.x == 0) out[(size_t)n * 40] = node_count;
    int wid = blockIdx.x * 4 + (threadIdx.x >> 6);
    int lane = threadIdx.x & 63;
    if (wid >= n) return;
    int s = off[wid], e = off[wid + 1];
    float acc = 0.f;
    int i = s;
    for (; i + 4 <= e; i += 4) {
        int u0 = esrc[i], u1 = esrc[i + 1], u2 = esrc[i + 2], u3 = esrc[i + 3];
        acc += b2f(P[(size_t)u0 * 64 + lane]) + b2f(P[(size_t)u1 * 64 + lane]) +
               b2f(P[(size_t)u2 * 64 + lane]) + b2f(P[(size_t)u3 * 64 + lane]);
    }
    for (; i < e; ++i) acc += b2f(P[(size_t)esrc[i] * 64 + lane]);

    float x = (lane < 40) ? acc + b3[lane] : -INFINITY;
    float m = x;
    for (int o = 32; o >= 1; o >>= 1) m = fmaxf(m, __shfl_xor(m, o));
    float ex = (lane < 40) ? expf(x - m) : 0.f;
    float ss = ex;
    for (int o = 32; o >= 1; o >>= 1) ss += __shfl_xor(ss, o);
    if (lane < 40) out[(size_t)wid * 40 + lane] = x - m - logf(ss);
}

// ---------------- launch ----------------

extern "C" void kernel_launch(void* const* d_in, const int* in_sizes, int n_in,
                              void* d_out, int out_size, void* d_ws, size_t ws_size,
                              hipStream_t stream) {
    const float* feat = (const float*)d_in[0];
    const int* ei = (const int*)d_in[1];
    const float* W1 = (const float*)d_in[4];
    const float* b1 = (const float*)d_in[5];
    const float* W2 = (const float*)d_in[6];
    const float* b2 = (const float*)d_in[7];
    const float* W3 = (const float*)d_in[8];
    const float* b3 = (const float*)d_in[9];

    const int N = in_sizes[0] / 256;
    const int E = in_sizes[1] / 2;
    const int* srcs = ei;
    const int* dsts = ei + E;

    char* ws = (char*)d_ws;
    size_t o = 0;
    auto alloc = [&](size_t bytes) {
        size_t r = o;
        o += (bytes + 255) & ~size_t(255);
        return r;
    };
    int* off    = (int*)(ws + alloc((size_t)(N + 1) * 4));
    int* cnt    = (int*)(ws + alloc((size_t)N * 4));
    int* pos    = (int*)(ws + alloc((size_t)N * 4));
    int* inc    = (int*)(ws + alloc((size_t)N * 4));
    int* bsum   = (int*)(ws + alloc(256 * 4));
    int* ebo    = (int*)(ws + alloc(256 * 4));
    int* esrc   = (int*)(ws + alloc((size_t)E * 4));
    short* featb = (short*)(ws + alloc((size_t)N * 256 * 2));  // blocked
    short* bufA  = (short*)(ws + alloc((size_t)N * 256 * 2));  // row-major
    short* bufB  = (short*)(ws + alloc((size_t)N * 256 * 2));  // blocked (L1 out) / row-major (L2 out)
    short* Wt1   = (short*)(ws + alloc(256 * 256 * 2));
    short* Wt2   = (short*)(ws + alloc(256 * 256 * 2));
    short* Wt3p  = (short*)(ws + alloc(64 * 256 * 2));
    short* Pbuf  = (short*)(ws + alloc((size_t)N * 64 * 2));
    (void)ws_size; (void)n_in; (void)out_size;

    const int NB = (N + 255) / 256;

    hipMemsetAsync(cnt, 0, (size_t)N * 4, stream);
    k_count<<<(E + 255) / 256, 256, 0, stream>>>(dsts, cnt, E);
    k_scan1<<<NB, 256, 0, stream>>>(cnt, inc, bsum, N);
    k_scan2<<<1, 256, 0, stream>>>(bsum, ebo, NB);
    k_scan3<<<NB, 256, 0, stream>>>(inc, cnt, ebo, off, pos, N);
    k_scatter<<<(E + 255) / 256, 256, 0, stream>>>(srcs, dsts, pos, esrc, E);

    k_cvt_blk<<<2048, 256, 0, stream>>>(feat, featb, N);
    k_cvt_weights<<<576, 256, 0, stream>>>(W1, W2, W3, Wt1, Wt2, Wt3p);

    const int aggSBlocks = 8 * ((N + 63) / 64);
    const int aggBlocks = (N + 3) / 4;
    const int gemmBlocks = (N + 63) / 64;

    k_agg_s<<<aggSBlocks, 256, 0, stream>>>(featb, off, esrc, bufA, N);
    k_gemm_mfma<1, 1><<<gemmBlocks, 256, 0, stream>>>(bufA, Wt1, b1, bufB, N);
    k_agg_s<<<aggSBlocks, 256, 0, stream>>>(bufB, off, esrc, bufA, N);
    k_gemm_mfma<1, 0><<<gemmBlocks, 256, 0, stream>>>(bufA, Wt2, b2, bufB, N);
    k_gemmP<<<gemmBlocks, 256, 0, stream>>>(bufB, Wt3p, Pbuf, N);
    k_aggout<<<aggBlocks, 256, 0, stream>>>(Pbuf, off, esrc, b3, (float*)d_out, N, 3.0f * (float)N);
}

// Round 16
// 407.445 us; speedup vs baseline: 1.0247x; 1.0247x over previous
//
#include <hip/hip_runtime.h>
#include <hip/hip_bf16.h>
#include <math.h>

// GCN bf16 pipeline (round 11):
//   CSR build (histogram/scan/scatter)
//   feat -> bf16 row-major ; W1,W2 -> bf16 [N][K] ; W3 -> bf16 padded [64][256]
//   agg1 = seg_sum(featb) ; h1 = relu(agg1@W1+b1)       (MFMA)
//   agg2 = seg_sum(h1)    ; h2 = relu(agg2@W2+b2)       (MFMA)
//   P = h2 @ W3                                          (MFMA, B in regs)
//   out = log_softmax(seg_sum(P) + b3) ; out[N*40] = 3N
// Aggregation: one wave per node, half-wave per edge, 16 B/lane, unroll x4
// -> 8 edges / 4 loads per lane in flight (ILP-depth test vs round 10's 2).

typedef __attribute__((ext_vector_type(8))) short bf16x8;
typedef __attribute__((ext_vector_type(4))) float f32x4;

static __device__ __forceinline__ short f2b(float f) {
    union { float f; unsigned u; } v; v.f = f;
    unsigned r = (v.u + 0x7FFFu + ((v.u >> 16) & 1u)) >> 16;
    return (short)r;
}
static __device__ __forceinline__ float b2f(short h) {
    union { unsigned u; float f; } v; v.u = ((unsigned)(unsigned short)h) << 16;
    return v.f;
}
static __device__ __forceinline__ bf16x8 bzero8() {
    bf16x8 v;
#pragma unroll
    for (int j = 0; j < 8; ++j) v[j] = 0;
    return v;
}

// ---------------- CSR build ----------------

__global__ __launch_bounds__(256) void k_count(const int* __restrict__ dst,
                                               int* __restrict__ cnt, int E) {
    int e = blockIdx.x * 256 + threadIdx.x;
    if (e < E) atomicAdd(&cnt[dst[e]], 1);
}

__global__ __launch_bounds__(256) void k_scan1(const int* __restrict__ cnt,
                                               int* __restrict__ inc,
                                               int* __restrict__ bsum, int n) {
    __shared__ int sh[256];
    int t = threadIdx.x;
    int i = blockIdx.x * 256 + t;
    int v = (i < n) ? cnt[i] : 0;
    sh[t] = v;
    __syncthreads();
    for (int s = 1; s < 256; s <<= 1) {
        int x = (t >= s) ? sh[t - s] : 0;
        __syncthreads();
        sh[t] += x;
        __syncthreads();
    }
    if (i < n) inc[i] = sh[t];
    if (t == 255) bsum[blockIdx.x] = sh[255];
}

__global__ __launch_bounds__(256) void k_scan2(const int* __restrict__ bsum,
                                               int* __restrict__ ebo, int nb) {
    __shared__ int sh[256];
    int t = threadIdx.x;
    int v = (t < nb) ? bsum[t] : 0;
    sh[t] = v;
    __syncthreads();
    for (int s = 1; s < 256; s <<= 1) {
        int x = (t >= s) ? sh[t - s] : 0;
        __syncthreads();
        sh[t] += x;
        __syncthreads();
    }
    ebo[t] = sh[t] - v;
}

__global__ __launch_bounds__(256) void k_scan3(const int* __restrict__ inc,
                                               const int* __restrict__ cnt,
                                               const int* __restrict__ ebo,
                                               int* __restrict__ off,
                                               int* __restrict__ pos, int n) {
    int i = blockIdx.x * 256 + threadIdx.x;
    if (i < n) {
        int ib = inc[i] + ebo[blockIdx.x];
        int ex = ib - cnt[i];
        off[i] = ex;
        pos[i] = ex;
        if (i == n - 1) off[n] = ib;
    }
}

__global__ __launch_bounds__(256) void k_scatter(const int* __restrict__ src,
                                                 const int* __restrict__ dst,
                                                 int* __restrict__ pos,
                                                 int* __restrict__ esrc, int E) {
    int e = blockIdx.x * 256 + threadIdx.x;
    if (e < E) {
        int p = atomicAdd(&pos[dst[e]], 1);
        esrc[p] = src[e];
    }
}

// ---------------- converts ----------------

__global__ __launch_bounds__(256) void k_cvt(const float* __restrict__ X,
                                             short* __restrict__ Y, int n4) {
    int i = blockIdx.x * 256 + threadIdx.x;
    int stride = gridDim.x * 256;
    for (; i < n4; i += stride) {
        float4 v = ((const float4*)X)[i];
        short4 o;
        o.x = f2b(v.x); o.y = f2b(v.y); o.z = f2b(v.z); o.w = f2b(v.w);
        ((short4*)Y)[i] = o;
    }
}

// fused weight converts: Wt1[n][k], Wt2[n][k] (256x256), Wt3p[c][k] (64x256, zero-padded)
__global__ __launch_bounds__(256) void k_cvt_weights(const float* __restrict__ W1,
                                                     const float* __restrict__ W2,
                                                     const float* __restrict__ W3,
                                                     short* __restrict__ Wt1,
                                                     short* __restrict__ Wt2,
                                                     short* __restrict__ Wt3p) {
    int b = blockIdx.x, t = threadIdx.x;
    if (b < 256) {
        int idx = b * 256 + t;
        int nn = idx >> 8, k = idx & 255;
        Wt1[idx] = f2b(W1[k * 256 + nn]);
    } else if (b < 512) {
        int idx = (b - 256) * 256 + t;
        int nn = idx >> 8, k = idx & 255;
        Wt2[idx] = f2b(W2[k * 256 + nn]);
    } else {
        int idx = (b - 512) * 256 + t;
        int c = idx >> 8, k = idx & 255;
        Wt3p[idx] = (c < 40) ? f2b(W3[k * 40 + c]) : (short)0;
    }
}

// ---------------- aggregation: one wave per node, half-wave per edge, unroll x4 ----------------
// lanes 0-31 take even-offset edges, lanes 32-63 odd; each lane loads 16 B (8 feats).
// 4 loads in flight per lane = 8 edges per iteration.

__global__ __launch_bounds__(256) void k_agg_w(const short* __restrict__ X,
                                               const int* __restrict__ off,
                                               const int* __restrict__ esrc,
                                               short* __restrict__ Y, int n) {
    int wid = blockIdx.x * 4 + (threadIdx.x >> 6);
    int lane = threadIdx.x & 63;
    int half = lane >> 5, hl = lane & 31;
    if (wid >= n) return;
    int s = off[wid], e = off[wid + 1];
    float acc[8];
#pragma unroll
    for (int j = 0; j < 8; ++j) acc[j] = 0.f;
    const short* __restrict__ Xb = X + hl * 8;
    int i = s + half;
    // main: 8 edges per iteration (4 per half-wave), 4 loads in flight
    for (; i + 6 < e; i += 8) {
        int u0 = esrc[i];
        int u1 = esrc[i + 2];
        int u2 = esrc[i + 4];
        int u3 = esrc[i + 6];
        bf16x8 v0 = *(const bf16x8*)&Xb[(size_t)u0 * 256];
        bf16x8 v1 = *(const bf16x8*)&Xb[(size_t)u1 * 256];
        bf16x8 v2 = *(const bf16x8*)&Xb[(size_t)u2 * 256];
        bf16x8 v3 = *(const bf16x8*)&Xb[(size_t)u3 * 256];
#pragma unroll
        for (int j = 0; j < 8; ++j)
            acc[j] += (b2f(v0[j]) + b2f(v1[j])) + (b2f(v2[j]) + b2f(v3[j]));
    }
    // tail: single edge per half-wave per step
    for (; i < e; i += 2) {
        int u0 = esrc[i];
        bf16x8 v0 = *(const bf16x8*)&Xb[(size_t)u0 * 256];
#pragma unroll
        for (int j = 0; j < 8; ++j) acc[j] += b2f(v0[j]);
    }
    // combine halves: lane hl += lane hl+32
#pragma unroll
    for (int j = 0; j < 8; ++j) acc[j] += __shfl_xor(acc[j], 32);
    if (half == 0) {
        bf16x8 o;
#pragma unroll
        for (int j = 0; j < 8; ++j) o[j] = f2b(acc[j]);
        *(bf16x8*)&Y[(size_t)wid * 256 + hl * 8] = o;
    }
}

// ---------------- MFMA GEMM: (M x 256) bf16 @ Wt[256][256] bf16 + bias, relu -> bf16 ----------------

template <int RELU>
__global__ __launch_bounds__(256) void k_gemm_mfma(const short* __restrict__ A,
                                                   const short* __restrict__ Wt,
                                                   const float* __restrict__ bias,
                                                   short* __restrict__ Y, int M) {
    __shared__ short smem[16384];  // 32 KB
    short* sA = smem;              // 2048 elems
    short* sB = smem + 2048;       // 8192 elems
    const int t = threadIdx.x;
    const int w = t >> 6, l = t & 63;
    const int lg = l >> 4, lr = l & 15;
    const int bm = blockIdx.x * 64;

    f32x4 acc[4][4];
#pragma unroll
    for (int a = 0; a < 4; ++a)
#pragma unroll
        for (int b = 0; b < 4; ++b) {
            acc[a][b][0] = 0.f; acc[a][b][1] = 0.f;
            acc[a][b][2] = 0.f; acc[a][b][3] = 0.f;
        }

    const int arow = bm + (t & 63);
    const int ag = t >> 6;
    const bool aok = (arow < M);

    bf16x8 ra, rb0, rb1, rb2, rb3;
    auto loadRegs = [&](int k0) {
        ra = aok ? *(const bf16x8*)&A[(size_t)arow * 256 + k0 + ag * 8] : bzero8();
        const short* wp = &Wt[(size_t)t * 256 + k0];
        rb0 = *(const bf16x8*)&wp[0];
        rb1 = *(const bf16x8*)&wp[8];
        rb2 = *(const bf16x8*)&wp[16];
        rb3 = *(const bf16x8*)&wp[24];
    };

    loadRegs(0);
    for (int kt = 0; kt < 8; ++kt) {
        __syncthreads();
        *(bf16x8*)&sA[t * 8] = ra;
        *(bf16x8*)&sB[t * 8] = rb0;
        *(bf16x8*)&sB[2048 + t * 8] = rb1;
        *(bf16x8*)&sB[4096 + t * 8] = rb2;
        *(bf16x8*)&sB[6144 + t * 8] = rb3;
        if (kt < 7) loadRegs((kt + 1) * 32);
        __syncthreads();

        bf16x8 af[4], bf[4];
#pragma unroll
        for (int rb = 0; rb < 4; ++rb)
            af[rb] = *(const bf16x8*)&sA[lg * 512 + (rb * 16 + lr) * 8];
#pragma unroll
        for (int cb = 0; cb < 4; ++cb)
            bf[cb] = *(const bf16x8*)&sB[lg * 2048 + ((w * 4 + cb) * 16 + lr) * 8];
#pragma unroll
        for (int rb = 0; rb < 4; ++rb)
#pragma unroll
            for (int cb = 0; cb < 4; ++cb)
                acc[rb][cb] = __builtin_amdgcn_mfma_f32_16x16x32_bf16(
                    af[rb], bf[cb], acc[rb][cb], 0, 0, 0);
    }

    __syncthreads();
    short* myreg = smem + w * 4096;  // wave-private [64][64]
#pragma unroll
    for (int cb = 0; cb < 4; ++cb) {
        float bb = bias[w * 64 + cb * 16 + lr];
#pragma unroll
        for (int rb = 0; rb < 4; ++rb)
#pragma unroll
            for (int r = 0; r < 4; ++r) {
                float x = acc[rb][cb][r] + bb;
                if (RELU) x = fmaxf(x, 0.f);
                myreg[(rb * 16 + lg * 4 + r) * 64 + cb * 16 + lr] = f2b(x);
            }
    }
#pragma unroll
    for (int j = 0; j < 8; ++j) {
        int row = j * 8 + (l >> 3);
        int grow = bm + row;
        bf16x8 v = *(const bf16x8*)&myreg[(j * 64 + l) * 8];
        if (grow < M)
            *(bf16x8*)&Y[(size_t)grow * 256 + w * 64 + (l & 7) * 8] = v;
    }
}

// ---------------- P GEMM: (M x 256) bf16 @ Wt3p[64][256] bf16 -> P (M x 64) bf16 ----------------

__global__ __launch_bounds__(256) void k_gemmP(const short* __restrict__ A,
                                               const short* __restrict__ Wt3p,
                                               short* __restrict__ P, int M) {
    __shared__ short sA[2048];  // 4 KB
    const int t = threadIdx.x;
    const int w = t >> 6, l = t & 63;
    const int lg = l >> 4, lr = l & 15;
    const int bm = blockIdx.x * 64;

    bf16x8 bfr[8];
#pragma unroll
    for (int kt = 0; kt < 8; ++kt)
        bfr[kt] = *(const bf16x8*)&Wt3p[(size_t)(w * 16 + lr) * 256 + kt * 32 + lg * 8];

    f32x4 acc[4];
#pragma unroll
    for (int a = 0; a < 4; ++a) {
        acc[a][0] = 0.f; acc[a][1] = 0.f; acc[a][2] = 0.f; acc[a][3] = 0.f;
    }

    const int arow = bm + l;
    const bool aok = (arow < M);
    bf16x8 ra = aok ? *(const bf16x8*)&A[(size_t)arow * 256 + w * 8] : bzero8();

#pragma unroll
    for (int kt = 0; kt < 8; ++kt) {
        __syncthreads();
        *(bf16x8*)&sA[t * 8] = ra;
        if (kt < 7)
            ra = aok ? *(const bf16x8*)&A[(size_t)arow * 256 + (kt + 1) * 32 + w * 8]
                     : bzero8();
        __syncthreads();
        bf16x8 af[4];
#pragma unroll
        for (int rb = 0; rb < 4; ++rb)
            af[rb] = *(const bf16x8*)&sA[lg * 512 + (rb * 16 + lr) * 8];
#pragma unroll
        for (int rb = 0; rb < 4; ++rb)
            acc[rb] = __builtin_amdgcn_mfma_f32_16x16x32_bf16(af[rb], bfr[kt], acc[rb], 0, 0, 0);
    }

#pragma unroll
    for (int rb = 0; rb < 4; ++rb)
#pragma unroll
        for (int r = 0; r < 4; ++r) {
            int grow = bm + rb * 16 + lg * 4 + r;
            if (grow < M)
                P[(size_t)grow * 64 + w * 16 + lr] = f2b(acc[rb][r]);
        }
}

// ---------------- fused agg3 + bias + log_softmax: one wave per node ----------------

__global__ __launch_bounds__(256) void k_aggout(const short* __restrict__ P,
                                                const int* __restrict__ off,
                                                const int* __restrict__ esrc,
                                                const float* __restrict__ b3,
                                                float* __restrict__ out, int n,
                                                float node_count) {
    if (blockIdx.x == 0 && threadIdx.x == 0) out[(size_t)n * 40] = node_count;
    int wid = blockIdx.x * 4 + (threadIdx.x >> 6);
    int lane = threadIdx.x & 63;
    if (wid >= n) return;
    int s = off[wid], e = off[wid + 1];
    float acc = 0.f;
    int i = s;
    for (; i + 4 <= e; i += 4) {
        int u0 = esrc[i], u1 = esrc[i + 1], u2 = esrc[i + 2], u3 = esrc[i + 3];
        acc += b2f(P[(size_t)u0 * 64 + lane]) + b2f(P[(size_t)u1 * 64 + lane]) +
               b2f(P[(size_t)u2 * 64 + lane]) + b2f(P[(size_t)u3 * 64 + lane]);
    }
    for (; i < e; ++i) acc += b2f(P[(size_t)esrc[i] * 64 + lane]);

    float x = (lane < 40) ? acc + b3[lane] : -INFINITY;
    float m = x;
    for (int o = 32; o >= 1; o >>= 1) m = fmaxf(m, __shfl_xor(m, o));
    float ex = (lane < 40) ? expf(x - m) : 0.f;
    float ss = ex;
    for (int o = 32; o >= 1; o >>= 1) ss += __shfl_xor(ss, o);
    if (lane < 40) out[(size_t)wid * 40 + lane] = x - m - logf(ss);
}

// ---------------- launch ----------------

extern "C" void kernel_launch(void* const* d_in, const int* in_sizes, int n_in,
                              void* d_out, int out_size, void* d_ws, size_t ws_size,
                              hipStream_t stream) {
    const float* feat = (const float*)d_in[0];
    const int* ei = (const int*)d_in[1];
    const float* W1 = (const float*)d_in[4];
    const float* b1 = (const float*)d_in[5];
    const float* W2 = (const float*)d_in[6];
    const float* b2 = (const float*)d_in[7];
    const float* W3 = (const float*)d_in[8];
    const float* b3 = (const float*)d_in[9];

    const int N = in_sizes[0] / 256;
    const int E = in_sizes[1] / 2;
    const int* srcs = ei;
    const int* dsts = ei + E;

    char* ws = (char*)d_ws;
    size_t o = 0;
    auto alloc = [&](size_t bytes) {
        size_t r = o;
        o += (bytes + 255) & ~size_t(255);
        return r;
    };
    int* off    = (int*)(ws + alloc((size_t)(N + 1) * 4));
    int* cnt    = (int*)(ws + alloc((size_t)N * 4));
    int* pos    = (int*)(ws + alloc((size_t)N * 4));
    int* inc    = (int*)(ws + alloc((size_t)N * 4));
    int* bsum   = (int*)(ws + alloc(256 * 4));
    int* ebo    = (int*)(ws + alloc(256 * 4));
    int* esrc   = (int*)(ws + alloc((size_t)E * 4));
    short* featb = (short*)(ws + alloc((size_t)N * 256 * 2));
    short* bufA  = (short*)(ws + alloc((size_t)N * 256 * 2));
    short* bufB  = (short*)(ws + alloc((size_t)N * 256 * 2));
    short* Wt1   = (short*)(ws + alloc(256 * 256 * 2));
    short* Wt2   = (short*)(ws + alloc(256 * 256 * 2));
    short* Wt3p  = (short*)(ws + alloc(64 * 256 * 2));
    short* Pbuf  = (short*)(ws + alloc((size_t)N * 64 * 2));
    (void)ws_size; (void)n_in; (void)out_size;

    const int NB = (N + 255) / 256;

    hipMemsetAsync(cnt, 0, (size_t)N * 4, stream);
    k_count<<<(E + 255) / 256, 256, 0, stream>>>(dsts, cnt, E);
    k_scan1<<<NB, 256, 0, stream>>>(cnt, inc, bsum, N);
    k_scan2<<<1, 256, 0, stream>>>(bsum, ebo, NB);
    k_scan3<<<NB, 256, 0, stream>>>(inc, cnt, ebo, off, pos, N);
    k_scatter<<<(E + 255) / 256, 256, 0, stream>>>(srcs, dsts, pos, esrc, E);

    k_cvt<<<2048, 256, 0, stream>>>(feat, featb, N * 64);
    k_cvt_weights<<<576, 256, 0, stream>>>(W1, W2, W3, Wt1, Wt2, Wt3p);

    const int aggBlocks = (N + 3) / 4;
    const int gemmBlocks = (N + 63) / 64;

    k_agg_w<<<aggBlocks, 256, 0, stream>>>(featb, off, esrc, bufA, N);
    k_gemm_mfma<1><<<gemmBlocks, 256, 0, stream>>>(bufA, Wt1, b1, bufB, N);
    k_agg_w<<<aggBlocks, 256, 0, stream>>>(bufB, off, esrc, bufA, N);
    k_gemm_mfma<1><<<gemmBlocks, 256, 0, stream>>>(bufA, Wt2, b2, bufB, N);
    k_gemmP<<<gemmBlocks, 256, 0, stream>>>(bufB, Wt3p, Pbuf, N);
    k_aggout<<<aggBlocks, 256, 0, stream>>>(Pbuf, off, esrc, b3, (float*)d_out, N, 3.0f * (float)N);
}